// Round 10
// baseline (253.723 us; speedup 1.0000x reference)
//
#include <hip/hip_runtime.h>
#include <hip/hip_bf16.h>

#define BN   2
#define SEQ  2048
#define DIM  1024
#define NH   16
#define HD   64
#define D4   4096
#define MAXS 4096

using bf16 = __hip_bfloat16;
typedef __bf16 bf16x8 __attribute__((ext_vector_type(8)));
typedef float  f32x4  __attribute__((ext_vector_type(4)));

__device__ __forceinline__ float bf2f(bf16 v){ return __bfloat162float(v); }
__device__ __forceinline__ bf16  f2bf(float v){ return __float2bfloat16(v); }
__device__ __forceinline__ float silu_f(float v){
  const float e = __expf(-v);
  return v * __builtin_amdgcn_rcpf(1.f + e);
}

__device__ __forceinline__ void async16(void* lds, const void* g){
  __builtin_amdgcn_global_load_lds((const __attribute__((address_space(1))) void*)g,
                                   (__attribute__((address_space(3))) void*)lds, 16, 0, 0);
}
__device__ __forceinline__ f32x4 mfma16(bf16x8 a, bf16x8 b, f32x4 c){
  return __builtin_amdgcn_mfma_f32_16x16x32_bf16(a, b, c, 0, 0, 0);
}

// ---------------- fp32 -> bf16 convert (3 arrays, 1 launch) ----------------
__global__ __launch_bounds__(256) void f2bk3(
    const float* __restrict__ a, bf16* __restrict__ ao, int na,
    const float* __restrict__ b, bf16* __restrict__ bo, int nb,
    const float* __restrict__ c, bf16* __restrict__ co)
{
  int i = (blockIdx.x * 256 + threadIdx.x) * 4;
  const float* in; bf16* out;
  if (i < na){ in = a; out = ao; }
  else if (i < na + nb){ in = b; out = bo; i -= na; }
  else { in = c; out = co; i -= na + nb; }
  const float4 v = *(const float4*)(in + i);
  bf16 t0 = f2bf(v.x), t1 = f2bf(v.y), t2 = f2bf(v.z), t3 = f2bf(v.w);
  ushort4 o;
  o.x = *(unsigned short*)&t0; o.y = *(unsigned short*)&t1;
  o.z = *(unsigned short*)&t2; o.w = *(unsigned short*)&t3;
  *(ushort4*)((unsigned short*)out + i) = o;
}

// ---------------- GEMM1: C = silu(A @ W^T + bias); v-tiles write transposed vt --------
// R15: 2-phase double-buffer (T3 minimum): stage NEXT BK=32 tile into buf^1 while
// computing CURRENT from buf[cur]; ONE drain-barrier per iteration. Staging latency
// hides under the 16 MFMAs + ds_reads. Barrier count unchanged vs R5 (32), but each
// drain now waits on loads issued a full compute-phase earlier. LDS 32KB (the two
// halves of Al/Bl are the dbuf pair), swizzles byte-identical, occupancy unchanged.
template<int NTOT>
__global__ __launch_bounds__(256) void gemm_bt(
    const bf16* __restrict__ A, const bf16* __restrict__ W,
    const float* __restrict__ bias, bf16* __restrict__ outb, bf16* __restrict__ vt)
{
  constexpr int K = DIM;
  constexpr int NIT = K / 32;
  const int ntiles = NTOT / 128;
  const int m0 = (int)(blockIdx.x / ntiles) * 128;
  const int n0 = (int)(blockIdx.x % ntiles) * 128;
  __shared__ bf16 Al[2*128*32];
  __shared__ bf16 Bl[2*128*32];
  const int tid = threadIdx.x, wave = tid>>6, lane = tid&63;
  const int quad = lane>>4, l16 = lane&15;
  const int srow = lane>>2;
  const int sg   = ((lane&3) ^ ((lane>>3)&3)) * 8;
  const int wm = (wave>>1)*64, wn = (wave&1)*64;
  const int rkey = ((l16>>1)&3);

  f32x4 acc[4][4];
  #pragma unroll
  for (int i=0;i<4;i++)
    #pragma unroll
    for (int j=0;j<4;j++) acc[i][j] = (f32x4){0.f,0.f,0.f,0.f};

  const bf16* aB = A + m0*K;
  const bf16* wB = W + n0*K;

  // prologue: stage tile 0 into buf 0
  {
    async16(&Al[wave*1024      ], aB + (wave*32      + srow)*K + sg);
    async16(&Al[wave*1024 + 512], aB + (wave*32 + 16 + srow)*K + sg);
    async16(&Bl[wave*1024      ], wB + (wave*32      + srow)*K + sg);
    async16(&Bl[wave*1024 + 512], wB + (wave*32 + 16 + srow)*K + sg);
  }
  __syncthreads();

  int cur = 0;
  for (int it = 0; it < NIT; ++it){
    // issue next-tile staging into the other buffer (overlaps this iter's compute)
    if (it + 1 < NIT){
      const int kc = (it+1)*32;
      const int nb = (cur^1)*4096;
      async16(&Al[nb + wave*1024      ], aB + (wave*32      + srow)*K + kc + sg);
      async16(&Al[nb + wave*1024 + 512], aB + (wave*32 + 16 + srow)*K + kc + sg);
      async16(&Bl[nb + wave*1024      ], wB + (wave*32      + srow)*K + kc + sg);
      async16(&Bl[nb + wave*1024 + 512], wB + (wave*32 + 16 + srow)*K + kc + sg);
    }
    // compute current buffer
    {
      const int cb = cur*4096;
      bf16x8 af[4], bv[4];
      #pragma unroll
      for (int mt=0;mt<4;mt++) af[mt] = *(const bf16x8*)&Al[cb + (wm+mt*16+l16)*32 + (quad ^ rkey)*8];
      #pragma unroll
      for (int nt=0;nt<4;nt++) bv[nt] = *(const bf16x8*)&Bl[cb + (wn+nt*16+l16)*32 + (quad ^ rkey)*8];
      #pragma unroll
      for (int mt=0;mt<4;mt++)
        #pragma unroll
        for (int nt=0;nt<4;nt++)
          acc[mt][nt] = mfma16(af[mt], bv[nt], acc[mt][nt]);
    }
    __syncthreads();   // drains vmcnt (next tile landed) + all waves done reading cur
    cur ^= 1;
  }

  const bool vtile = (NTOT == 4096) && (n0 >= 3*DIM);
  if (!vtile){
    #pragma unroll
    for (int mt=0;mt<4;mt++){
      #pragma unroll
      for (int nt=0;nt<4;nt++){
        const int row = m0 + wm + mt*16 + quad*4;
        const int col = n0 + wn + nt*16 + l16;
        const float bvv = bias[col];
        #pragma unroll
        for (int r=0;r<4;r++){
          float v = silu_f(acc[mt][nt][r] + bvv);
          outb[(row+r)*NTOT + col] = f2bf(v);
        }
      }
    }
  } else {
    // v slice: write transposed directly to vt[b][hh][d][s] (4 consecutive s -> 8B store)
    #pragma unroll
    for (int mt=0;mt<4;mt++){
      #pragma unroll
      for (int nt=0;nt<4;nt++){
        const int row = m0 + wm + mt*16 + quad*4;
        const int colg = n0 + wn + nt*16 + l16;
        const float bvv = bias[colg];
        const int col = colg - 3*DIM;
        const int hh = col >> 6, d = col & 63;
        const int bb = row >> 11, sl = row & 2047;
        ushort4 o;
        float v0 = silu_f(acc[mt][nt][0] + bvv);
        float v1 = silu_f(acc[mt][nt][1] + bvv);
        float v2 = silu_f(acc[mt][nt][2] + bvv);
        float v3 = silu_f(acc[mt][nt][3] + bvv);
        bf16 t0=f2bf(v0), t1=f2bf(v1), t2=f2bf(v2), t3=f2bf(v3);
        o.x=*(unsigned short*)&t0; o.y=*(unsigned short*)&t1;
        o.z=*(unsigned short*)&t2; o.w=*(unsigned short*)&t3;
        *(ushort4*)&vt[((bb*NH + hh)*HD + d)*SEQ + sl] = o;
      }
    }
  }
}

// ---------------- GEMM2: z = A @ W^T + bias + resid; 2-phase dbuf, 24KB LDS ---------
__global__ __launch_bounds__(256) void gemm_bt2(
    const bf16* __restrict__ A, const bf16* __restrict__ W,
    const float* __restrict__ bias, const float* __restrict__ resid,
    float* __restrict__ outf)
{
  constexpr int K = DIM, NTOT = DIM;
  constexpr int NIT = K / 32;
  const int ntiles = NTOT / 64;
  const int m0 = (int)(blockIdx.x / ntiles) * 128;
  const int n0 = (int)(blockIdx.x % ntiles) * 64;
  __shared__ bf16 Al[2*128*32];
  __shared__ bf16 Bl[2*64*32];
  const int tid = threadIdx.x, wave = tid>>6, lane = tid&63;
  const int quad = lane>>4, l16 = lane&15;
  const int srow = lane>>2;
  const int sg   = ((lane&3) ^ ((lane>>3)&3)) * 8;
  const int wm = wave*32;
  const int rkey = ((l16>>1)&3);

  f32x4 acc[2][4];
  #pragma unroll
  for (int i=0;i<2;i++)
    #pragma unroll
    for (int j=0;j<4;j++) acc[i][j] = (f32x4){0.f,0.f,0.f,0.f};

  const bf16* aB = A + m0*K;
  const bf16* wB = W + n0*K;

  // prologue: stage tile 0 into buf 0
  {
    async16(&Al[wave*1024      ], aB + (wave*32      + srow)*K + sg);
    async16(&Al[wave*1024 + 512], aB + (wave*32 + 16 + srow)*K + sg);
    async16(&Bl[wave*512       ], wB + (wave*16      + srow)*K + sg);
  }
  __syncthreads();

  int cur = 0;
  for (int it = 0; it < NIT; ++it){
    if (it + 1 < NIT){
      const int kc = (it+1)*32;
      async16(&Al[(cur^1)*4096 + wave*1024      ], aB + (wave*32      + srow)*K + kc + sg);
      async16(&Al[(cur^1)*4096 + wave*1024 + 512], aB + (wave*32 + 16 + srow)*K + kc + sg);
      async16(&Bl[(cur^1)*2048 + wave*512       ], wB + (wave*16      + srow)*K + kc + sg);
    }
    {
      bf16x8 af[2], bv[4];
      #pragma unroll
      for (int mt=0;mt<2;mt++) af[mt] = *(const bf16x8*)&Al[cur*4096 + (wm+mt*16+l16)*32 + (quad ^ rkey)*8];
      #pragma unroll
      for (int nt=0;nt<4;nt++) bv[nt] = *(const bf16x8*)&Bl[cur*2048 + (nt*16+l16)*32 + (quad ^ rkey)*8];
      #pragma unroll
      for (int mt=0;mt<2;mt++)
        #pragma unroll
        for (int nt=0;nt<4;nt++)
          acc[mt][nt] = mfma16(af[mt], bv[nt], acc[mt][nt]);
    }
    __syncthreads();
    cur ^= 1;
  }

  #pragma unroll
  for (int mt=0;mt<2;mt++){
    #pragma unroll
    for (int nt=0;nt<4;nt++){
      const int row = m0 + wm + mt*16 + quad*4;
      const int col = n0 + nt*16 + l16;
      const float bvv = bias[col];
      #pragma unroll
      for (int r=0;r<4;r++){
        outf[(row+r)*NTOT + col] = acc[mt][nt][r] + bvv + resid[(row+r)*NTOT + col];
      }
    }
  }
}

// ---------------- attention (R15 = R7 restored: best verified attn) ----------------
// grid 1024 = 32 (b,h) groups x 32 q-tiles. g = bid&31 (group g's blocks all have
// bid%8 = g%8 -> stable XCD affinity). qt = 31-(bid>>5): global LPT, 16-iter blocks
// first, 1-iter tail backfills. Separate Pl (50KB LDS, 3 blocks/CU).
// Lessons kept: V LDS-staged (R6: V-from-global -> +35us); full-batch P (R8:
// quarter-split PV serialized the write->read chain -> +3.4us); no waves-per-EU
// hint (R2: VGPR cap -> spill). T14 reg-prefetch + T5 setprio.
__global__ __launch_bounds__(256) void attn(
    const bf16* __restrict__ h, const bf16* __restrict__ vt,
    const float* __restrict__ pw, bf16* __restrict__ y)
{
  const int bid = blockIdx.x;
  const int g  = bid & 31;                 // (b,head) group 0..31
  const int qt = 31 - (bid >> 5);          // global longest-first
  const int hh = g & 15, b = g >> 4;

  // Kl: [128 kpos][64 d] (16KB). Vl: [64 d][128 kpos] (16KB).
  // Pl: [4 waves][16 qrow * 136] (17408B). pwl: 256 f32 (1KB). Total 50.0KB.
  __shared__ __align__(16) char smem[16384 + 16384 + 17408 + 1024];
  bf16*  Kl  = (bf16*)smem;
  bf16*  Vl  = (bf16*)(smem + 16384);
  bf16*  Pl  = (bf16*)(smem + 32768);
  float* pwl = (float*)(smem + 50176);

  const int tid = threadIdx.x, wave = tid>>6, lane = tid&63;
  const int quad = lane>>4, l16 = lane&15;

  const bf16* kgb = h + b*SEQ*D4 + 2*DIM + hh*HD;
  const bf16* vgb = vt + (b*NH + hh)*HD*SEQ;
  const int krow8 = lane>>3;
  const int kgo   = ((lane&7) ^ krow8) * 8;
  const int vrow4 = lane>>4;

  const int q0 = qt * 64;

  const bf16* qbase = h + (b*SEQ + q0 + wave*16 + l16)*D4 + DIM + hh*HD;
  bf16x8 qf[2];
  qf[0] = *(const bf16x8*)(qbase + quad*8);
  qf[1] = *(const bf16x8*)(qbase + 32 + quad*8);

  f32x4 oacc[4];
  #pragma unroll
  for (int nt=0;nt<4;nt++) oacc[nt] = (f32x4){0.f,0.f,0.f,0.f};

  const int kmax = q0 + 64;

  // ---- prologue prefetch (k0 = 0) into regs ----
  bf16x8 kreg[4], vreg[4];
  float pv;
  #pragma unroll
  for (int t=0;t<4;t++)
    kreg[t] = *(const bf16x8*)(kgb + (wave*32 + t*8 + krow8)*D4 + kgo);
  #pragma unroll
  for (int t=0;t<4;t++){
    const int vg = ((lane&15) ^ (t*4 + vrow4)) * 8;
    vreg[t] = *(const bf16x8*)(vgb + (wave*16 + t*4 + vrow4)*SEQ + vg);
  }
  pv = pw[MAXS - 1 - q0 - 63 + tid];

  for (int k0 = 0; k0 < kmax; k0 += 128){
    __syncthreads();   // b1: all waves done reading Kl/Vl/pwl from previous iter
    // reg -> LDS (linear dest, source swizzle applied at the global load)
    #pragma unroll
    for (int t=0;t<4;t++)
      *(bf16x8*)&Kl[(wave*32 + t*8)*64 + lane*8] = kreg[t];
    #pragma unroll
    for (int t=0;t<4;t++)
      *(bf16x8*)&Vl[(wave*16 + t*4)*128 + lane*8] = vreg[t];
    pwl[tid] = pv;
    __syncthreads();   // b2: staged tile visible

    // ---- prefetch NEXT tile into regs; latency hides under this iter's compute ----
    if (k0 + 128 < kmax){
      const int kn = k0 + 128;
      #pragma unroll
      for (int t=0;t<4;t++)
        kreg[t] = *(const bf16x8*)(kgb + (kn + wave*32 + t*8 + krow8)*D4 + kgo);
      #pragma unroll
      for (int t=0;t<4;t++){
        const int vg = ((lane&15) ^ (t*4 + vrow4)) * 8;
        vreg[t] = *(const bf16x8*)(vgb + (wave*16 + t*4 + vrow4)*SEQ + kn + vg);
      }
      pv = pw[MAXS - 1 + kn - q0 - 63 + tid];
    }

    // S^T = K @ Q^T  (m=128 kpos as 8 nt-frags, n=16 qrows, k=64)
    f32x4 sacc[8];
    #pragma unroll
    for (int nt=0;nt<8;nt++) sacc[nt] = (f32x4){0.f,0.f,0.f,0.f};
    __builtin_amdgcn_s_setprio(1);
    #pragma unroll
    for (int ks=0;ks<2;ks++){
      #pragma unroll
      for (int nt=0;nt<8;nt++){
        bf16x8 kf = *(const bf16x8*)&Kl[(nt*16 + l16)*64 + ((ks*4 + quad) ^ (l16&7))*8];
        sacc[nt] = mfma16(kf, qf[ks], sacc[nt]);   // A=K, B=Q^T  -> C = S^T
      }
    }
    __builtin_amdgcn_s_setprio(0);

    // bias + silu + causal; lane holds 4 consecutive kpos for fixed qrow=l16
    bf16* Plw = Pl + wave*(16*136);
    const int dq = q0 - k0;
    const int qrl = wave*16 + l16;
    if (dq >= 127){
      // full tile: no causal select (wave-uniform branch)
      #pragma unroll
      for (int nt=0;nt<8;nt++){
        const int kb = nt*16 + quad*4;
        ushort4 o; bf16 tb[4];
        #pragma unroll
        for (int r=0;r<4;r++){
          const int d = kb + r - qrl;
          const float bias = pwl[d + 63];
          tb[r] = f2bf(silu_f(sacc[nt][r] + bias));
        }
        o.x=*(unsigned short*)&tb[0]; o.y=*(unsigned short*)&tb[1];
        o.z=*(unsigned short*)&tb[2]; o.w=*(unsigned short*)&tb[3];
        *(ushort4*)&Plw[l16*136 + kb] = o;
      }
    } else {
      #pragma unroll
      for (int nt=0;nt<8;nt++){
        const int kb = nt*16 + quad*4;
        ushort4 o; bf16 tb[4];
        #pragma unroll
        for (int r=0;r<4;r++){
          const int d = kb + r - qrl;
          const float bias = pwl[d + 63];
          const float sv = silu_f(sacc[nt][r] + bias);
          tb[r] = f2bf((d <= dq) ? sv : 0.f);
        }
        o.x=*(unsigned short*)&tb[0]; o.y=*(unsigned short*)&tb[1];
        o.z=*(unsigned short*)&tb[2]; o.w=*(unsigned short*)&tb[3];
        *(ushort4*)&Plw[l16*136 + kb] = o;
      }
    }

    // O += P @ V  (m=16 qrows, n=64 d, k=128 kpos); Pl[wave] read-after-write is
    // same-wave in-order LDS, no barrier needed.
    __builtin_amdgcn_s_setprio(1);
    #pragma unroll
    for (int ks=0;ks<4;ks++){
      bf16x8 pf = *(const bf16x8*)&Plw[l16*136 + ks*32 + quad*8];
      #pragma unroll
      for (int nt=0;nt<4;nt++){
        bf16x8 vf = *(const bf16x8*)&Vl[(nt*16 + l16)*128 + ((ks*4 + quad) ^ l16)*8];
        oacc[nt] = mfma16(pf, vf, oacc[nt]);
      }
    }
    __builtin_amdgcn_s_setprio(0);
  }

  // epilogue: multiply by u, write y
  const int qrow = q0 + wave*16 + quad*4;
  #pragma unroll
  for (int nt=0;nt<4;nt++){
    const int c = hh*HD + nt*16 + l16;
    #pragma unroll
    for (int r=0;r<4;r++){
      const int srow = b*SEQ + qrow + r;
      const float uu = bf2f(h[srow*D4 + c]);
      y[srow*DIM + c] = f2bf(oacc[nt][r] * uu);
    }
  }
}

// NOTE on pwl indexing: d = (kb + r) - (wave*16 + l16), window W0 = MAXS-1+k0-q0-63
// gives pwl[d + 63] with d in [-63, 127] -> idx in [0,190]. W0+tid stays within
// pw's 2*MAXS-1 = 8191 entries (W0 in [2048,4032], +255 max = 4287).

// ---------------- row layernorm over D=1024 ----------------
template<bool FP32IN, bool FP32OUT>
__global__ __launch_bounds__(256) void lnorm(const void* __restrict__ in,
    const float* __restrict__ g, const float* __restrict__ be, void* __restrict__ out)
{
  const int row = blockIdx.x;
  const int tid = threadIdx.x, wave = tid>>6, lane = tid&63;
  const int c0 = tid*4;
  float v[4];
  if (FP32IN){
    const float* p = (const float*)in + row*DIM + c0;
    #pragma unroll
    for (int j=0;j<4;j++) v[j] = p[j];
  } else {
    const bf16* p = (const bf16*)in + row*DIM + c0;
    #pragma unroll
    for (int j=0;j<4;j++) v[j] = bf2f(p[j]);
  }
  float s = 0.f, ss = 0.f;
  #pragma unroll
  for (int j=0;j<4;j++){ s += v[j]; ss += v[j]*v[j]; }
  #pragma unroll
  for (int off=32; off>0; off>>=1){
    s  += __shfl_down(s, off);
    ss += __shfl_down(ss, off);
  }
  __shared__ float red[8];
  if (lane==0){ red[wave] = s; red[4+wave] = ss; }
  __syncthreads();
  s  = red[0]+red[1]+red[2]+red[3];
  ss = red[4]+red[5]+red[6]+red[7];
  const float mu   = s * (1.f/DIM);
  const float var  = ss * (1.f/DIM) - mu*mu;
  const float rstd = rsqrtf(var + 1e-5f);
  #pragma unroll
  for (int j=0;j<4;j++){
    const int c = c0 + j;
    const float o = (v[j]-mu)*rstd*g[c] + be[c];
    if (FP32OUT) ((float*)out)[row*DIM + c] = o;
    else         ((bf16*)out)[row*DIM + c] = f2bf(o);
  }
}

extern "C" void kernel_launch(void* const* d_in, const int* in_sizes, int n_in,
                              void* d_out, int out_size, void* d_ws, size_t ws_size,
                              hipStream_t stream)
{
  const float* x   = (const float*)d_in[0];
  const float* w1  = (const float*)d_in[2];
  const float* b1  = (const float*)d_in[3];
  const float* w2  = (const float*)d_in[4];
  const float* b2  = (const float*)d_in[5];
  const float* g1  = (const float*)d_in[6];
  const float* be1 = (const float*)d_in[7];
  const float* g2  = (const float*)d_in[8];
  const float* be2 = (const float*)d_in[9];
  const float* pw  = (const float*)d_in[10];

  char* ws = (char*)d_ws;
  bf16*  h   = (bf16*)(ws);
  bf16*  vt  = (bf16*)(ws + (32u<<20));
  bf16*  y   = (bf16*)(ws + (40u<<20));
  bf16*  xb  = (bf16*)(ws + (48u<<20));
  bf16*  w1b = (bf16*)(ws + (56u<<20));
  bf16*  w2b = (bf16*)(ws + (64u<<20));
  bf16*  l1  = (bf16*)(ws + (66u<<20));
  float* z   = (float*)(ws + (74u<<20));

  const int NX  = BN*SEQ*DIM;
  const int NW1 = 4*DIM*DIM;
  const int NW2 = DIM*DIM;
  f2bk3<<<dim3((NX+NW1+NW2)/1024), dim3(256), 0, stream>>>(x, xb, NX, w1, w1b, NW1, w2, w2b);

  gemm_bt<4096><<<dim3(1024), dim3(256), 0, stream>>>(xb, w1b, b1, h, vt);
  attn<<<dim3(1024), dim3(256), 0, stream>>>(h, vt, pw, y);
  lnorm<false,false><<<dim3(4096), dim3(256), 0, stream>>>(y, g1, be1, l1);
  gemm_bt2<<<dim3(512), dim3(256), 0, stream>>>(l1, w2b, b2, x, z);
  lnorm<true,true><<<dim3(4096), dim3(256), 0, stream>>>(z, g2, be2, d_out);
}

// Round 12
// 234.796 us; speedup vs baseline: 1.0806x; 1.0806x over previous
//
#include <hip/hip_runtime.h>
#include <hip/hip_bf16.h>

#define BN   2
#define SEQ  2048
#define DIM  1024
#define NH   16
#define HD   64
#define D4   4096
#define MAXS 4096

using bf16 = __hip_bfloat16;
typedef __bf16 bf16x8 __attribute__((ext_vector_type(8)));
typedef float  f32x4  __attribute__((ext_vector_type(4)));

__device__ __forceinline__ float bf2f(bf16 v){ return __bfloat162float(v); }
__device__ __forceinline__ bf16  f2bf(float v){ return __float2bfloat16(v); }
__device__ __forceinline__ float silu_f(float v){
  const float e = __expf(-v);
  return v * __builtin_amdgcn_rcpf(1.f + e);
}

__device__ __forceinline__ void async16(void* lds, const void* g){
  __builtin_amdgcn_global_load_lds((const __attribute__((address_space(1))) void*)g,
                                   (__attribute__((address_space(3))) void*)lds, 16, 0, 0);
}
__device__ __forceinline__ f32x4 mfma16(bf16x8 a, bf16x8 b, f32x4 c){
  return __builtin_amdgcn_mfma_f32_16x16x32_bf16(a, b, c, 0, 0, 0);
}

// ---------------- fp32 -> bf16 convert (3 arrays, 1 launch) ----------------
__global__ __launch_bounds__(256) void f2bk3(
    const float* __restrict__ a, bf16* __restrict__ ao, int na,
    const float* __restrict__ b, bf16* __restrict__ bo, int nb,
    const float* __restrict__ c, bf16* __restrict__ co)
{
  int i = (blockIdx.x * 256 + threadIdx.x) * 4;
  const float* in; bf16* out;
  if (i < na){ in = a; out = ao; }
  else if (i < na + nb){ in = b; out = bo; i -= na; }
  else { in = c; out = co; i -= na + nb; }
  const float4 v = *(const float4*)(in + i);
  bf16 t0 = f2bf(v.x), t1 = f2bf(v.y), t2 = f2bf(v.z), t3 = f2bf(v.w);
  ushort4 o;
  o.x = *(unsigned short*)&t0; o.y = *(unsigned short*)&t1;
  o.z = *(unsigned short*)&t2; o.w = *(unsigned short*)&t3;
  *(ushort4*)((unsigned short*)out + i) = o;
}

// ---------------- GEMM1: C = silu(A @ W^T + bias); v-tiles write transposed vt --------
// R5 structure (verified best): BK=64 as two contiguous BK=32 sub-tiles; batch-stage
// both, ONE exposed vmcnt drain per 32 MFMAs/wave. (R9 lesson: __syncthreads always
// drains vmcnt(0) — HIP-level dbuf prefetch just doubles drain frequency; don't.)
template<int NTOT>
__global__ __launch_bounds__(256) void gemm_bt(
    const bf16* __restrict__ A, const bf16* __restrict__ W,
    const float* __restrict__ bias, bf16* __restrict__ outb, bf16* __restrict__ vt)
{
  constexpr int K = DIM;
  const int ntiles = NTOT / 128;
  const int m0 = (int)(blockIdx.x / ntiles) * 128;
  const int n0 = (int)(blockIdx.x % ntiles) * 128;
  __shared__ bf16 Al[2*128*32];
  __shared__ bf16 Bl[2*128*32];
  const int tid = threadIdx.x, wave = tid>>6, lane = tid&63;
  const int quad = lane>>4, l16 = lane&15;
  const int srow = lane>>2;
  const int sg   = ((lane&3) ^ ((lane>>3)&3)) * 8;
  const int wm = (wave>>1)*64, wn = (wave&1)*64;
  const int rkey = ((l16>>1)&3);

  f32x4 acc[4][4];
  #pragma unroll
  for (int i=0;i<4;i++)
    #pragma unroll
    for (int j=0;j<4;j++) acc[i][j] = (f32x4){0.f,0.f,0.f,0.f};

  const bf16* aB = A + m0*K;
  const bf16* wB = W + n0*K;

  for (int k0 = 0; k0 < K; k0 += 64){
    #pragma unroll
    for (int s=0;s<2;s++){
      const int kc = k0 + s*32;
      async16(&Al[s*4096 + wave*1024      ], aB + (wave*32      + srow)*K + kc + sg);
      async16(&Al[s*4096 + wave*1024 + 512], aB + (wave*32 + 16 + srow)*K + kc + sg);
      async16(&Bl[s*4096 + wave*1024      ], wB + (wave*32      + srow)*K + kc + sg);
      async16(&Bl[s*4096 + wave*1024 + 512], wB + (wave*32 + 16 + srow)*K + kc + sg);
    }
    __syncthreads();
    #pragma unroll
    for (int s=0;s<2;s++){
      bf16x8 af[4], bv[4];
      #pragma unroll
      for (int mt=0;mt<4;mt++) af[mt] = *(const bf16x8*)&Al[s*4096 + (wm+mt*16+l16)*32 + (quad ^ rkey)*8];
      #pragma unroll
      for (int nt=0;nt<4;nt++) bv[nt] = *(const bf16x8*)&Bl[s*4096 + (wn+nt*16+l16)*32 + (quad ^ rkey)*8];
      #pragma unroll
      for (int mt=0;mt<4;mt++)
        #pragma unroll
        for (int nt=0;nt<4;nt++)
          acc[mt][nt] = mfma16(af[mt], bv[nt], acc[mt][nt]);
    }
    __syncthreads();
  }

  const bool vtile = (NTOT == 4096) && (n0 >= 3*DIM);
  if (!vtile){
    #pragma unroll
    for (int mt=0;mt<4;mt++){
      #pragma unroll
      for (int nt=0;nt<4;nt++){
        const int row = m0 + wm + mt*16 + quad*4;
        const int col = n0 + wn + nt*16 + l16;
        const float bvv = bias[col];
        #pragma unroll
        for (int r=0;r<4;r++){
          float v = silu_f(acc[mt][nt][r] + bvv);
          outb[(row+r)*NTOT + col] = f2bf(v);
        }
      }
    }
  } else {
    // v slice: write transposed directly to vt[b][hh][d][s] (4 consecutive s -> 8B store)
    #pragma unroll
    for (int mt=0;mt<4;mt++){
      #pragma unroll
      for (int nt=0;nt<4;nt++){
        const int row = m0 + wm + mt*16 + quad*4;
        const int colg = n0 + wn + nt*16 + l16;
        const float bvv = bias[colg];
        const int col = colg - 3*DIM;
        const int hh = col >> 6, d = col & 63;
        const int bb = row >> 11, sl = row & 2047;
        ushort4 o;
        float v0 = silu_f(acc[mt][nt][0] + bvv);
        float v1 = silu_f(acc[mt][nt][1] + bvv);
        float v2 = silu_f(acc[mt][nt][2] + bvv);
        float v3 = silu_f(acc[mt][nt][3] + bvv);
        bf16 t0=f2bf(v0), t1=f2bf(v1), t2=f2bf(v2), t3=f2bf(v3);
        o.x=*(unsigned short*)&t0; o.y=*(unsigned short*)&t1;
        o.z=*(unsigned short*)&t2; o.w=*(unsigned short*)&t3;
        *(ushort4*)&vt[((bb*NH + hh)*HD + d)*SEQ + sl] = o;
      }
    }
  }
}

// ---------------- GEMM2: z = A @ W^T + bias + resid, 128x64 tile, fp32 out ----------
// R16: BK=128 as FOUR contiguous BK=32 sub-tiles. Grid 512 = 2 blocks/CU is
// grid-capped, so the 48KB LDS costs no occupancy (m132's BK=128 regression was
// occupancy-driven; doesn't apply). Barriers 32 -> 16; 32 MFMA/wave per drain.
__global__ __launch_bounds__(256) void gemm_bt2(
    const bf16* __restrict__ A, const bf16* __restrict__ W,
    const float* __restrict__ bias, const float* __restrict__ resid,
    float* __restrict__ outf)
{
  constexpr int K = DIM, NTOT = DIM;
  const int ntiles = NTOT / 64;
  const int m0 = (int)(blockIdx.x / ntiles) * 128;
  const int n0 = (int)(blockIdx.x % ntiles) * 64;
  __shared__ bf16 Al[4*128*32];
  __shared__ bf16 Bl[4*64*32];
  const int tid = threadIdx.x, wave = tid>>6, lane = tid&63;
  const int quad = lane>>4, l16 = lane&15;
  const int srow = lane>>2;
  const int sg   = ((lane&3) ^ ((lane>>3)&3)) * 8;
  const int wm = wave*32;
  const int rkey = ((l16>>1)&3);

  f32x4 acc[2][4];
  #pragma unroll
  for (int i=0;i<2;i++)
    #pragma unroll
    for (int j=0;j<4;j++) acc[i][j] = (f32x4){0.f,0.f,0.f,0.f};

  const bf16* aB = A + m0*K;
  const bf16* wB = W + n0*K;

  for (int k0 = 0; k0 < K; k0 += 128){
    #pragma unroll
    for (int s=0;s<4;s++){
      const int kc = k0 + s*32;
      async16(&Al[s*4096 + wave*1024      ], aB + (wave*32      + srow)*K + kc + sg);
      async16(&Al[s*4096 + wave*1024 + 512], aB + (wave*32 + 16 + srow)*K + kc + sg);
      async16(&Bl[s*2048 + wave*512       ], wB + (wave*16      + srow)*K + kc + sg);
    }
    __syncthreads();
    #pragma unroll
    for (int s=0;s<4;s++){
      bf16x8 af[2], bv[4];
      #pragma unroll
      for (int mt=0;mt<2;mt++) af[mt] = *(const bf16x8*)&Al[s*4096 + (wm+mt*16+l16)*32 + (quad ^ rkey)*8];
      #pragma unroll
      for (int nt=0;nt<4;nt++) bv[nt] = *(const bf16x8*)&Bl[s*2048 + (nt*16+l16)*32 + (quad ^ rkey)*8];
      #pragma unroll
      for (int mt=0;mt<2;mt++)
        #pragma unroll
        for (int nt=0;nt<4;nt++)
          acc[mt][nt] = mfma16(af[mt], bv[nt], acc[mt][nt]);
    }
    __syncthreads();
  }

  #pragma unroll
  for (int mt=0;mt<2;mt++){
    #pragma unroll
    for (int nt=0;nt<4;nt++){
      const int row = m0 + wm + mt*16 + quad*4;
      const int col = n0 + nt*16 + l16;
      const float bvv = bias[col];
      #pragma unroll
      for (int r=0;r<4;r++){
        outf[(row+r)*NTOT + col] = acc[mt][nt][r] + bvv + resid[(row+r)*NTOT + col];
      }
    }
  }
}

// ---------------- attention (R7 verbatim: best verified attn) ----------------
// grid 1024 = 32 (b,h) groups x 32 q-tiles. g = bid&31 (XCD affinity), qt =
// 31-(bid>>5) (global LPT + backfill tail). Separate Pl (50KB LDS, 3 blocks/CU).
// Lessons: V LDS-staged (R6); full-batch P (R8); no waves-per-EU hint (R2).
__global__ __launch_bounds__(256) void attn(
    const bf16* __restrict__ h, const bf16* __restrict__ vt,
    const float* __restrict__ pw, bf16* __restrict__ y)
{
  const int bid = blockIdx.x;
  const int g  = bid & 31;                 // (b,head) group 0..31
  const int qt = 31 - (bid >> 5);          // global longest-first
  const int hh = g & 15, b = g >> 4;

  __shared__ __align__(16) char smem[16384 + 16384 + 17408 + 1024];
  bf16*  Kl  = (bf16*)smem;
  bf16*  Vl  = (bf16*)(smem + 16384);
  bf16*  Pl  = (bf16*)(smem + 32768);
  float* pwl = (float*)(smem + 50176);

  const int tid = threadIdx.x, wave = tid>>6, lane = tid&63;
  const int quad = lane>>4, l16 = lane&15;

  const bf16* kgb = h + b*SEQ*D4 + 2*DIM + hh*HD;
  const bf16* vgb = vt + (b*NH + hh)*HD*SEQ;
  const int krow8 = lane>>3;
  const int kgo   = ((lane&7) ^ krow8) * 8;
  const int vrow4 = lane>>4;

  const int q0 = qt * 64;

  const bf16* qbase = h + (b*SEQ + q0 + wave*16 + l16)*D4 + DIM + hh*HD;
  bf16x8 qf[2];
  qf[0] = *(const bf16x8*)(qbase + quad*8);
  qf[1] = *(const bf16x8*)(qbase + 32 + quad*8);

  f32x4 oacc[4];
  #pragma unroll
  for (int nt=0;nt<4;nt++) oacc[nt] = (f32x4){0.f,0.f,0.f,0.f};

  const int kmax = q0 + 64;

  // ---- prologue prefetch (k0 = 0) into regs ----
  bf16x8 kreg[4], vreg[4];
  float pv;
  #pragma unroll
  for (int t=0;t<4;t++)
    kreg[t] = *(const bf16x8*)(kgb + (wave*32 + t*8 + krow8)*D4 + kgo);
  #pragma unroll
  for (int t=0;t<4;t++){
    const int vg = ((lane&15) ^ (t*4 + vrow4)) * 8;
    vreg[t] = *(const bf16x8*)(vgb + (wave*16 + t*4 + vrow4)*SEQ + vg);
  }
  pv = pw[MAXS - 1 - q0 - 63 + tid];

  for (int k0 = 0; k0 < kmax; k0 += 128){
    __syncthreads();   // b1: all waves done reading Kl/Vl/pwl from previous iter
    #pragma unroll
    for (int t=0;t<4;t++)
      *(bf16x8*)&Kl[(wave*32 + t*8)*64 + lane*8] = kreg[t];
    #pragma unroll
    for (int t=0;t<4;t++)
      *(bf16x8*)&Vl[(wave*16 + t*4)*128 + lane*8] = vreg[t];
    pwl[tid] = pv;
    __syncthreads();   // b2: staged tile visible

    if (k0 + 128 < kmax){
      const int kn = k0 + 128;
      #pragma unroll
      for (int t=0;t<4;t++)
        kreg[t] = *(const bf16x8*)(kgb + (kn + wave*32 + t*8 + krow8)*D4 + kgo);
      #pragma unroll
      for (int t=0;t<4;t++){
        const int vg = ((lane&15) ^ (t*4 + vrow4)) * 8;
        vreg[t] = *(const bf16x8*)(vgb + (wave*16 + t*4 + vrow4)*SEQ + kn + vg);
      }
      pv = pw[MAXS - 1 + kn - q0 - 63 + tid];
    }

    // S^T = K @ Q^T  (m=128 kpos as 8 nt-frags, n=16 qrows, k=64)
    f32x4 sacc[8];
    #pragma unroll
    for (int nt=0;nt<8;nt++) sacc[nt] = (f32x4){0.f,0.f,0.f,0.f};
    __builtin_amdgcn_s_setprio(1);
    #pragma unroll
    for (int ks=0;ks<2;ks++){
      #pragma unroll
      for (int nt=0;nt<8;nt++){
        bf16x8 kf = *(const bf16x8*)&Kl[(nt*16 + l16)*64 + ((ks*4 + quad) ^ (l16&7))*8];
        sacc[nt] = mfma16(kf, qf[ks], sacc[nt]);   // A=K, B=Q^T  -> C = S^T
      }
    }
    __builtin_amdgcn_s_setprio(0);

    // bias + silu + causal; lane holds 4 consecutive kpos for fixed qrow=l16
    bf16* Plw = Pl + wave*(16*136);
    const int dq = q0 - k0;
    const int qrl = wave*16 + l16;
    if (dq >= 127){
      #pragma unroll
      for (int nt=0;nt<8;nt++){
        const int kb = nt*16 + quad*4;
        ushort4 o; bf16 tb[4];
        #pragma unroll
        for (int r=0;r<4;r++){
          const int d = kb + r - qrl;
          const float bias = pwl[d + 63];
          tb[r] = f2bf(silu_f(sacc[nt][r] + bias));
        }
        o.x=*(unsigned short*)&tb[0]; o.y=*(unsigned short*)&tb[1];
        o.z=*(unsigned short*)&tb[2]; o.w=*(unsigned short*)&tb[3];
        *(ushort4*)&Plw[l16*136 + kb] = o;
      }
    } else {
      #pragma unroll
      for (int nt=0;nt<8;nt++){
        const int kb = nt*16 + quad*4;
        ushort4 o; bf16 tb[4];
        #pragma unroll
        for (int r=0;r<4;r++){
          const int d = kb + r - qrl;
          const float bias = pwl[d + 63];
          const float sv = silu_f(sacc[nt][r] + bias);
          tb[r] = f2bf((d <= dq) ? sv : 0.f);
        }
        o.x=*(unsigned short*)&tb[0]; o.y=*(unsigned short*)&tb[1];
        o.z=*(unsigned short*)&tb[2]; o.w=*(unsigned short*)&tb[3];
        *(ushort4*)&Plw[l16*136 + kb] = o;
      }
    }

    // O += P @ V  (m=16 qrows, n=64 d, k=128 kpos); same-wave LDS RAW, no barrier.
    __builtin_amdgcn_s_setprio(1);
    #pragma unroll
    for (int ks=0;ks<4;ks++){
      bf16x8 pf = *(const bf16x8*)&Plw[l16*136 + ks*32 + quad*8];
      #pragma unroll
      for (int nt=0;nt<4;nt++){
        bf16x8 vf = *(const bf16x8*)&Vl[(nt*16 + l16)*128 + ((ks*4 + quad) ^ l16)*8];
        oacc[nt] = mfma16(pf, vf, oacc[nt]);
      }
    }
    __builtin_amdgcn_s_setprio(0);
  }

  // epilogue: multiply by u, write y
  const int qrow = q0 + wave*16 + quad*4;
  #pragma unroll
  for (int nt=0;nt<4;nt++){
    const int c = hh*HD + nt*16 + l16;
    #pragma unroll
    for (int r=0;r<4;r++){
      const int srow = b*SEQ + qrow + r;
      const float uu = bf2f(h[srow*D4 + c]);
      y[srow*DIM + c] = f2bf(oacc[nt][r] * uu);
    }
  }
}

// NOTE on pwl indexing: d = (kb + r) - (wave*16 + l16), window W0 = MAXS-1+k0-q0-63
// gives pwl[d + 63] with d in [-63, 127] -> idx in [0,190]. W0+tid stays within
// pw's 2*MAXS-1 = 8191 entries (W0 in [2048,4032], +255 max = 4287).

// ---------------- row layernorm over D=1024 ----------------
template<bool FP32IN, bool FP32OUT>
__global__ __launch_bounds__(256) void lnorm(const void* __restrict__ in,
    const float* __restrict__ g, const float* __restrict__ be, void* __restrict__ out)
{
  const int row = blockIdx.x;
  const int tid = threadIdx.x, wave = tid>>6, lane = tid&63;
  const int c0 = tid*4;
  float v[4];
  if (FP32IN){
    const float* p = (const float*)in + row*DIM + c0;
    #pragma unroll
    for (int j=0;j<4;j++) v[j] = p[j];
  } else {
    const bf16* p = (const bf16*)in + row*DIM + c0;
    #pragma unroll
    for (int j=0;j<4;j++) v[j] = bf2f(p[j]);
  }
  float s = 0.f, ss = 0.f;
  #pragma unroll
  for (int j=0;j<4;j++){ s += v[j]; ss += v[j]*v[j]; }
  #pragma unroll
  for (int off=32; off>0; off>>=1){
    s  += __shfl_down(s, off);
    ss += __shfl_down(ss, off);
  }
  __shared__ float red[8];
  if (lane==0){ red[wave] = s; red[4+wave] = ss; }
  __syncthreads();
  s  = red[0]+red[1]+red[2]+red[3];
  ss = red[4]+red[5]+red[6]+red[7];
  const float mu   = s * (1.f/DIM);
  const float var  = ss * (1.f/DIM) - mu*mu;
  const float rstd = rsqrtf(var + 1e-5f);
  #pragma unroll
  for (int j=0;j<4;j++){
    const int c = c0 + j;
    const float o = (v[j]-mu)*rstd*g[c] + be[c];
    if (FP32OUT) ((float*)out)[row*DIM + c] = o;
    else         ((bf16*)out)[row*DIM + c] = f2bf(o);
  }
}

extern "C" void kernel_launch(void* const* d_in, const int* in_sizes, int n_in,
                              void* d_out, int out_size, void* d_ws, size_t ws_size,
                              hipStream_t stream)
{
  const float* x   = (const float*)d_in[0];
  const float* w1  = (const float*)d_in[2];
  const float* b1  = (const float*)d_in[3];
  const float* w2  = (const float*)d_in[4];
  const float* b2  = (const float*)d_in[5];
  const float* g1  = (const float*)d_in[6];
  const float* be1 = (const float*)d_in[7];
  const float* g2  = (const float*)d_in[8];
  const float* be2 = (const float*)d_in[9];
  const float* pw  = (const float*)d_in[10];

  char* ws = (char*)d_ws;
  bf16*  h   = (bf16*)(ws);
  bf16*  vt  = (bf16*)(ws + (32u<<20));
  bf16*  y   = (bf16*)(ws + (40u<<20));
  bf16*  xb  = (bf16*)(ws + (48u<<20));
  bf16*  w1b = (bf16*)(ws + (56u<<20));
  bf16*  w2b = (bf16*)(ws + (64u<<20));
  bf16*  l1  = (bf16*)(ws + (66u<<20));
  float* z   = (float*)(ws + (74u<<20));

  const int NX  = BN*SEQ*DIM;
  const int NW1 = 4*DIM*DIM;
  const int NW2 = DIM*DIM;
  f2bk3<<<dim3((NX+NW1+NW2)/1024), dim3(256), 0, stream>>>(x, xb, NX, w1, w1b, NW1, w2, w2b);

  gemm_bt<4096><<<dim3(1024), dim3(256), 0, stream>>>(xb, w1b, b1, h, vt);
  attn<<<dim3(1024), dim3(256), 0, stream>>>(h, vt, pw, y);
  lnorm<false,false><<<dim3(4096), dim3(256), 0, stream>>>(y, g1, be1, l1);
  gemm_bt2<<<dim3(512), dim3(256), 0, stream>>>(l1, w2b, b2, x, z);
  lnorm<true,true><<<dim3(4096), dim3(256), 0, stream>>>(z, g2, be2, d_out);
}

// Round 13
// 233.218 us; speedup vs baseline: 1.0879x; 1.0068x over previous
//
#include <hip/hip_runtime.h>
#include <hip/hip_bf16.h>

#define BN   2
#define SEQ  2048
#define DIM  1024
#define NH   16
#define HD   64
#define D4   4096
#define MAXS 4096

using bf16 = __hip_bfloat16;
typedef __bf16 bf16x8 __attribute__((ext_vector_type(8)));
typedef float  f32x4  __attribute__((ext_vector_type(4)));
typedef unsigned short us8 __attribute__((ext_vector_type(8)));

__device__ __forceinline__ float bf2f(bf16 v){ return __bfloat162float(v); }
__device__ __forceinline__ bf16  f2bf(float v){ return __float2bfloat16(v); }
__device__ __forceinline__ float silu_f(float v){
  const float e = __expf(-v);
  return v * __builtin_amdgcn_rcpf(1.f + e);
}

__device__ __forceinline__ void async16(void* lds, const void* g){
  __builtin_amdgcn_global_load_lds((const __attribute__((address_space(1))) void*)g,
                                   (__attribute__((address_space(3))) void*)lds, 16, 0, 0);
}
__device__ __forceinline__ f32x4 mfma16(bf16x8 a, bf16x8 b, f32x4 c){
  return __builtin_amdgcn_mfma_f32_16x16x32_bf16(a, b, c, 0, 0, 0);
}

// ---------------- fp32 -> bf16 convert (3 arrays, 1 launch; 8 floats/thread) --------
__global__ __launch_bounds__(256) void f2bk3(
    const float* __restrict__ a, bf16* __restrict__ ao, int na,
    const float* __restrict__ b, bf16* __restrict__ bo, int nb,
    const float* __restrict__ c, bf16* __restrict__ co)
{
  int i = (blockIdx.x * 256 + threadIdx.x) * 8;
  const float* in; bf16* out;
  if (i < na){ in = a; out = ao; }
  else if (i < na + nb){ in = b; out = bo; i -= na; }
  else { in = c; out = co; i -= na + nb; }
  const float4 v0 = *(const float4*)(in + i);
  const float4 v1 = *(const float4*)(in + i + 4);
  us8 o;
  bf16 t;
  t = f2bf(v0.x); o[0] = *(unsigned short*)&t;
  t = f2bf(v0.y); o[1] = *(unsigned short*)&t;
  t = f2bf(v0.z); o[2] = *(unsigned short*)&t;
  t = f2bf(v0.w); o[3] = *(unsigned short*)&t;
  t = f2bf(v1.x); o[4] = *(unsigned short*)&t;
  t = f2bf(v1.y); o[5] = *(unsigned short*)&t;
  t = f2bf(v1.z); o[6] = *(unsigned short*)&t;
  t = f2bf(v1.w); o[7] = *(unsigned short*)&t;
  *(us8*)((unsigned short*)out + i) = o;
}

// ---------------- GEMM1: C = silu(A @ W^T + bias); v-tiles write transposed vt --------
// R5 structure (verified best): BK=64 as two contiguous BK=32 sub-tiles; batch-stage
// both, ONE exposed vmcnt drain per 32 MFMAs/wave. (R9 lesson: __syncthreads always
// drains vmcnt(0) — HIP-level dbuf prefetch just doubles drain frequency; don't.)
template<int NTOT>
__global__ __launch_bounds__(256) void gemm_bt(
    const bf16* __restrict__ A, const bf16* __restrict__ W,
    const float* __restrict__ bias, bf16* __restrict__ outb, bf16* __restrict__ vt)
{
  constexpr int K = DIM;
  const int ntiles = NTOT / 128;
  const int m0 = (int)(blockIdx.x / ntiles) * 128;
  const int n0 = (int)(blockIdx.x % ntiles) * 128;
  __shared__ bf16 Al[2*128*32];
  __shared__ bf16 Bl[2*128*32];
  const int tid = threadIdx.x, wave = tid>>6, lane = tid&63;
  const int quad = lane>>4, l16 = lane&15;
  const int srow = lane>>2;
  const int sg   = ((lane&3) ^ ((lane>>3)&3)) * 8;
  const int wm = (wave>>1)*64, wn = (wave&1)*64;
  const int rkey = ((l16>>1)&3);

  f32x4 acc[4][4];
  #pragma unroll
  for (int i=0;i<4;i++)
    #pragma unroll
    for (int j=0;j<4;j++) acc[i][j] = (f32x4){0.f,0.f,0.f,0.f};

  const bf16* aB = A + m0*K;
  const bf16* wB = W + n0*K;

  for (int k0 = 0; k0 < K; k0 += 64){
    #pragma unroll
    for (int s=0;s<2;s++){
      const int kc = k0 + s*32;
      async16(&Al[s*4096 + wave*1024      ], aB + (wave*32      + srow)*K + kc + sg);
      async16(&Al[s*4096 + wave*1024 + 512], aB + (wave*32 + 16 + srow)*K + kc + sg);
      async16(&Bl[s*4096 + wave*1024      ], wB + (wave*32      + srow)*K + kc + sg);
      async16(&Bl[s*4096 + wave*1024 + 512], wB + (wave*32 + 16 + srow)*K + kc + sg);
    }
    __syncthreads();
    #pragma unroll
    for (int s=0;s<2;s++){
      bf16x8 af[4], bv[4];
      #pragma unroll
      for (int mt=0;mt<4;mt++) af[mt] = *(const bf16x8*)&Al[s*4096 + (wm+mt*16+l16)*32 + (quad ^ rkey)*8];
      #pragma unroll
      for (int nt=0;nt<4;nt++) bv[nt] = *(const bf16x8*)&Bl[s*4096 + (wn+nt*16+l16)*32 + (quad ^ rkey)*8];
      #pragma unroll
      for (int mt=0;mt<4;mt++)
        #pragma unroll
        for (int nt=0;nt<4;nt++)
          acc[mt][nt] = mfma16(af[mt], bv[nt], acc[mt][nt]);
    }
    __syncthreads();
  }

  const bool vtile = (NTOT == 4096) && (n0 >= 3*DIM);
  if (!vtile){
    #pragma unroll
    for (int mt=0;mt<4;mt++){
      #pragma unroll
      for (int nt=0;nt<4;nt++){
        const int row = m0 + wm + mt*16 + quad*4;
        const int col = n0 + wn + nt*16 + l16;
        const float bvv = bias[col];
        #pragma unroll
        for (int r=0;r<4;r++){
          float v = silu_f(acc[mt][nt][r] + bvv);
          outb[(row+r)*NTOT + col] = f2bf(v);
        }
      }
    }
  } else {
    // v slice: write transposed directly to vt[b][hh][d][s] (4 consecutive s -> 8B store)
    #pragma unroll
    for (int mt=0;mt<4;mt++){
      #pragma unroll
      for (int nt=0;nt<4;nt++){
        const int row = m0 + wm + mt*16 + quad*4;
        const int colg = n0 + wn + nt*16 + l16;
        const float bvv = bias[colg];
        const int col = colg - 3*DIM;
        const int hh = col >> 6, d = col & 63;
        const int bb = row >> 11, sl = row & 2047;
        ushort4 o;
        float v0 = silu_f(acc[mt][nt][0] + bvv);
        float v1 = silu_f(acc[mt][nt][1] + bvv);
        float v2 = silu_f(acc[mt][nt][2] + bvv);
        float v3 = silu_f(acc[mt][nt][3] + bvv);
        bf16 t0=f2bf(v0), t1=f2bf(v1), t2=f2bf(v2), t3=f2bf(v3);
        o.x=*(unsigned short*)&t0; o.y=*(unsigned short*)&t1;
        o.z=*(unsigned short*)&t2; o.w=*(unsigned short*)&t3;
        *(ushort4*)&vt[((bb*NH + hh)*HD + d)*SEQ + sl] = o;
      }
    }
  }
}

// ---------------- GEMM2: z = A @ W^T + bias + resid, 128x64 tile, fp32 out ----------
// BK=128 as FOUR contiguous BK=32 sub-tiles (R11: verified pass). Grid 512 = 2
// blocks/CU grid-capped, so the 48KB LDS costs no occupancy. 16 barrier-pairs.
__global__ __launch_bounds__(256) void gemm_bt2(
    const bf16* __restrict__ A, const bf16* __restrict__ W,
    const float* __restrict__ bias, const float* __restrict__ resid,
    float* __restrict__ outf)
{
  constexpr int K = DIM, NTOT = DIM;
  const int ntiles = NTOT / 64;
  const int m0 = (int)(blockIdx.x / ntiles) * 128;
  const int n0 = (int)(blockIdx.x % ntiles) * 64;
  __shared__ bf16 Al[4*128*32];
  __shared__ bf16 Bl[4*64*32];
  const int tid = threadIdx.x, wave = tid>>6, lane = tid&63;
  const int quad = lane>>4, l16 = lane&15;
  const int srow = lane>>2;
  const int sg   = ((lane&3) ^ ((lane>>3)&3)) * 8;
  const int wm = wave*32;
  const int rkey = ((l16>>1)&3);

  f32x4 acc[2][4];
  #pragma unroll
  for (int i=0;i<2;i++)
    #pragma unroll
    for (int j=0;j<4;j++) acc[i][j] = (f32x4){0.f,0.f,0.f,0.f};

  const bf16* aB = A + m0*K;
  const bf16* wB = W + n0*K;

  for (int k0 = 0; k0 < K; k0 += 128){
    #pragma unroll
    for (int s=0;s<4;s++){
      const int kc = k0 + s*32;
      async16(&Al[s*4096 + wave*1024      ], aB + (wave*32      + srow)*K + kc + sg);
      async16(&Al[s*4096 + wave*1024 + 512], aB + (wave*32 + 16 + srow)*K + kc + sg);
      async16(&Bl[s*2048 + wave*512       ], wB + (wave*16      + srow)*K + kc + sg);
    }
    __syncthreads();
    #pragma unroll
    for (int s=0;s<4;s++){
      bf16x8 af[2], bv[4];
      #pragma unroll
      for (int mt=0;mt<2;mt++) af[mt] = *(const bf16x8*)&Al[s*4096 + (wm+mt*16+l16)*32 + (quad ^ rkey)*8];
      #pragma unroll
      for (int nt=0;nt<4;nt++) bv[nt] = *(const bf16x8*)&Bl[s*2048 + (nt*16+l16)*32 + (quad ^ rkey)*8];
      #pragma unroll
      for (int mt=0;mt<2;mt++)
        #pragma unroll
        for (int nt=0;nt<4;nt++)
          acc[mt][nt] = mfma16(af[mt], bv[nt], acc[mt][nt]);
    }
    __syncthreads();
  }

  #pragma unroll
  for (int mt=0;mt<2;mt++){
    #pragma unroll
    for (int nt=0;nt<4;nt++){
      const int row = m0 + wm + mt*16 + quad*4;
      const int col = n0 + nt*16 + l16;
      const float bvv = bias[col];
      #pragma unroll
      for (int r=0;r<4;r++){
        outf[(row+r)*NTOT + col] = acc[mt][nt][r] + bvv + resid[(row+r)*NTOT + col];
      }
    }
  }
}

// ---------------- attention (R7 verbatim: best verified attn) ----------------
// grid 1024 = 32 (b,h) groups x 32 q-tiles. g = bid&31 (XCD affinity), qt =
// 31-(bid>>5) (global LPT + backfill tail). Separate Pl (50KB LDS, 3 blocks/CU).
// Lessons: V LDS-staged (R6); full-batch P (R8); no waves-per-EU hint (R2).
__global__ __launch_bounds__(256) void attn(
    const bf16* __restrict__ h, const bf16* __restrict__ vt,
    const float* __restrict__ pw, bf16* __restrict__ y)
{
  const int bid = blockIdx.x;
  const int g  = bid & 31;                 // (b,head) group 0..31
  const int qt = 31 - (bid >> 5);          // global longest-first
  const int hh = g & 15, b = g >> 4;

  __shared__ __align__(16) char smem[16384 + 16384 + 17408 + 1024];
  bf16*  Kl  = (bf16*)smem;
  bf16*  Vl  = (bf16*)(smem + 16384);
  bf16*  Pl  = (bf16*)(smem + 32768);
  float* pwl = (float*)(smem + 50176);

  const int tid = threadIdx.x, wave = tid>>6, lane = tid&63;
  const int quad = lane>>4, l16 = lane&15;

  const bf16* kgb = h + b*SEQ*D4 + 2*DIM + hh*HD;
  const bf16* vgb = vt + (b*NH + hh)*HD*SEQ;
  const int krow8 = lane>>3;
  const int kgo   = ((lane&7) ^ krow8) * 8;
  const int vrow4 = lane>>4;

  const int q0 = qt * 64;

  const bf16* qbase = h + (b*SEQ + q0 + wave*16 + l16)*D4 + DIM + hh*HD;
  bf16x8 qf[2];
  qf[0] = *(const bf16x8*)(qbase + quad*8);
  qf[1] = *(const bf16x8*)(qbase + 32 + quad*8);

  f32x4 oacc[4];
  #pragma unroll
  for (int nt=0;nt<4;nt++) oacc[nt] = (f32x4){0.f,0.f,0.f,0.f};

  const int kmax = q0 + 64;

  // ---- prologue prefetch (k0 = 0) into regs ----
  bf16x8 kreg[4], vreg[4];
  float pv;
  #pragma unroll
  for (int t=0;t<4;t++)
    kreg[t] = *(const bf16x8*)(kgb + (wave*32 + t*8 + krow8)*D4 + kgo);
  #pragma unroll
  for (int t=0;t<4;t++){
    const int vg = ((lane&15) ^ (t*4 + vrow4)) * 8;
    vreg[t] = *(const bf16x8*)(vgb + (wave*16 + t*4 + vrow4)*SEQ + vg);
  }
  pv = pw[MAXS - 1 - q0 - 63 + tid];

  for (int k0 = 0; k0 < kmax; k0 += 128){
    __syncthreads();   // b1: all waves done reading Kl/Vl/pwl from previous iter
    #pragma unroll
    for (int t=0;t<4;t++)
      *(bf16x8*)&Kl[(wave*32 + t*8)*64 + lane*8] = kreg[t];
    #pragma unroll
    for (int t=0;t<4;t++)
      *(bf16x8*)&Vl[(wave*16 + t*4)*128 + lane*8] = vreg[t];
    pwl[tid] = pv;
    __syncthreads();   // b2: staged tile visible

    if (k0 + 128 < kmax){
      const int kn = k0 + 128;
      #pragma unroll
      for (int t=0;t<4;t++)
        kreg[t] = *(const bf16x8*)(kgb + (kn + wave*32 + t*8 + krow8)*D4 + kgo);
      #pragma unroll
      for (int t=0;t<4;t++){
        const int vg = ((lane&15) ^ (t*4 + vrow4)) * 8;
        vreg[t] = *(const bf16x8*)(vgb + (wave*16 + t*4 + vrow4)*SEQ + kn + vg);
      }
      pv = pw[MAXS - 1 + kn - q0 - 63 + tid];
    }

    // S^T = K @ Q^T  (m=128 kpos as 8 nt-frags, n=16 qrows, k=64)
    f32x4 sacc[8];
    #pragma unroll
    for (int nt=0;nt<8;nt++) sacc[nt] = (f32x4){0.f,0.f,0.f,0.f};
    __builtin_amdgcn_s_setprio(1);
    #pragma unroll
    for (int ks=0;ks<2;ks++){
      #pragma unroll
      for (int nt=0;nt<8;nt++){
        bf16x8 kf = *(const bf16x8*)&Kl[(nt*16 + l16)*64 + ((ks*4 + quad) ^ (l16&7))*8];
        sacc[nt] = mfma16(kf, qf[ks], sacc[nt]);   // A=K, B=Q^T  -> C = S^T
      }
    }
    __builtin_amdgcn_s_setprio(0);

    // bias + silu + causal; lane holds 4 consecutive kpos for fixed qrow=l16
    bf16* Plw = Pl + wave*(16*136);
    const int dq = q0 - k0;
    const int qrl = wave*16 + l16;
    if (dq >= 127){
      #pragma unroll
      for (int nt=0;nt<8;nt++){
        const int kb = nt*16 + quad*4;
        ushort4 o; bf16 tb[4];
        #pragma unroll
        for (int r=0;r<4;r++){
          const int d = kb + r - qrl;
          const float bias = pwl[d + 63];
          tb[r] = f2bf(silu_f(sacc[nt][r] + bias));
        }
        o.x=*(unsigned short*)&tb[0]; o.y=*(unsigned short*)&tb[1];
        o.z=*(unsigned short*)&tb[2]; o.w=*(unsigned short*)&tb[3];
        *(ushort4*)&Plw[l16*136 + kb] = o;
      }
    } else {
      #pragma unroll
      for (int nt=0;nt<8;nt++){
        const int kb = nt*16 + quad*4;
        ushort4 o; bf16 tb[4];
        #pragma unroll
        for (int r=0;r<4;r++){
          const int d = kb + r - qrl;
          const float bias = pwl[d + 63];
          const float sv = silu_f(sacc[nt][r] + bias);
          tb[r] = f2bf((d <= dq) ? sv : 0.f);
        }
        o.x=*(unsigned short*)&tb[0]; o.y=*(unsigned short*)&tb[1];
        o.z=*(unsigned short*)&tb[2]; o.w=*(unsigned short*)&tb[3];
        *(ushort4*)&Plw[l16*136 + kb] = o;
      }
    }

    // O += P @ V  (m=16 qrows, n=64 d, k=128 kpos); same-wave LDS RAW, no barrier.
    __builtin_amdgcn_s_setprio(1);
    #pragma unroll
    for (int ks=0;ks<4;ks++){
      bf16x8 pf = *(const bf16x8*)&Plw[l16*136 + ks*32 + quad*8];
      #pragma unroll
      for (int nt=0;nt<4;nt++){
        bf16x8 vf = *(const bf16x8*)&Vl[(nt*16 + l16)*128 + ((ks*4 + quad) ^ l16)*8];
        oacc[nt] = mfma16(pf, vf, oacc[nt]);
      }
    }
    __builtin_amdgcn_s_setprio(0);
  }

  // epilogue: multiply by u, write y
  const int qrow = q0 + wave*16 + quad*4;
  #pragma unroll
  for (int nt=0;nt<4;nt++){
    const int c = hh*HD + nt*16 + l16;
    #pragma unroll
    for (int r=0;r<4;r++){
      const int srow = b*SEQ + qrow + r;
      const float uu = bf2f(h[srow*D4 + c]);
      y[srow*DIM + c] = f2bf(oacc[nt][r] * uu);
    }
  }
}

// NOTE on pwl indexing: d = (kb + r) - (wave*16 + l16), window W0 = MAXS-1+k0-q0-63
// gives pwl[d + 63] with d in [-63, 127] -> idx in [0,190]. W0+tid stays within
// pw's 2*MAXS-1 = 8191 entries (W0 in [2048,4032], +255 max = 4287).

// ---------------- row layernorm over D=1024 (R18: wave-per-row, no LDS/barriers) ----
// 4 rows/block (wave w owns row bid*4+w); lane holds 16 elems in 16B vector chunks
// (chunk j: elems j*CH + lane*VL). __shfl_xor butterfly gives every lane the row
// sums. Vectorized g/beta loads. Replaces 2-barrier scalar-load version (scalar
// bf16 loads ~2x tax, Common-mistake #2).
template<bool FP32>
__global__ __launch_bounds__(256) void lnorm(const void* __restrict__ in,
    const float* __restrict__ g, const float* __restrict__ be, void* __restrict__ out)
{
  const int wave = threadIdx.x>>6, lane = threadIdx.x&63;
  const int row = blockIdx.x*4 + wave;
  float v[16];
  if (FP32){
    const float* p = (const float*)in + row*DIM;
    #pragma unroll
    for (int j=0;j<4;j++){
      const float4 t = *(const float4*)(p + j*256 + lane*4);
      v[j*4+0]=t.x; v[j*4+1]=t.y; v[j*4+2]=t.z; v[j*4+3]=t.w;
    }
  } else {
    const unsigned short* p = (const unsigned short*)in + row*DIM;
    #pragma unroll
    for (int j=0;j<2;j++){
      const us8 t = *(const us8*)(p + j*512 + lane*8);
      #pragma unroll
      for (int k=0;k<8;k++){
        unsigned short u = t[k];
        v[j*8+k] = bf2f(*(bf16*)&u);
      }
    }
  }
  float s = 0.f, ss = 0.f;
  #pragma unroll
  for (int e=0;e<16;e++){ s += v[e]; ss += v[e]*v[e]; }
  #pragma unroll
  for (int off=1; off<64; off<<=1){
    s  += __shfl_xor(s, off);
    ss += __shfl_xor(ss, off);
  }
  const float mu   = s * (1.f/DIM);
  const float var  = ss * (1.f/DIM) - mu*mu;
  const float rstd = rsqrtf(var + 1e-5f);
  if (FP32){
    float* q = (float*)out + row*DIM;
    #pragma unroll
    for (int j=0;j<4;j++){
      const int c = j*256 + lane*4;
      const float4 gv = *(const float4*)(g + c);
      const float4 bv = *(const float4*)(be + c);
      float4 o;
      o.x = (v[j*4+0]-mu)*rstd*gv.x + bv.x;
      o.y = (v[j*4+1]-mu)*rstd*gv.y + bv.y;
      o.z = (v[j*4+2]-mu)*rstd*gv.z + bv.z;
      o.w = (v[j*4+3]-mu)*rstd*gv.w + bv.w;
      *(float4*)(q + c) = o;
    }
  } else {
    unsigned short* q = (unsigned short*)out + row*DIM;
    #pragma unroll
    for (int j=0;j<2;j++){
      const int c = j*512 + lane*8;
      us8 o;
      #pragma unroll
      for (int k=0;k<8;k++){
        const float ov = (v[j*8+k]-mu)*rstd*g[c+k] + be[c+k];
        bf16 t = f2bf(ov);
        o[k] = *(unsigned short*)&t;
      }
      *(us8*)(q + c) = o;
    }
  }
}

extern "C" void kernel_launch(void* const* d_in, const int* in_sizes, int n_in,
                              void* d_out, int out_size, void* d_ws, size_t ws_size,
                              hipStream_t stream)
{
  const float* x   = (const float*)d_in[0];
  const float* w1  = (const float*)d_in[2];
  const float* b1  = (const float*)d_in[3];
  const float* w2  = (const float*)d_in[4];
  const float* b2  = (const float*)d_in[5];
  const float* g1  = (const float*)d_in[6];
  const float* be1 = (const float*)d_in[7];
  const float* g2  = (const float*)d_in[8];
  const float* be2 = (const float*)d_in[9];
  const float* pw  = (const float*)d_in[10];

  char* ws = (char*)d_ws;
  bf16*  h   = (bf16*)(ws);
  bf16*  vt  = (bf16*)(ws + (32u<<20));
  bf16*  y   = (bf16*)(ws + (40u<<20));
  bf16*  xb  = (bf16*)(ws + (48u<<20));
  bf16*  w1b = (bf16*)(ws + (56u<<20));
  bf16*  w2b = (bf16*)(ws + (64u<<20));
  bf16*  l1  = (bf16*)(ws + (66u<<20));
  float* z   = (float*)(ws + (74u<<20));

  const int NX  = BN*SEQ*DIM;
  const int NW1 = 4*DIM*DIM;
  const int NW2 = DIM*DIM;
  f2bk3<<<dim3((NX+NW1+NW2)/2048), dim3(256), 0, stream>>>(x, xb, NX, w1, w1b, NW1, w2, w2b);

  gemm_bt<4096><<<dim3(1024), dim3(256), 0, stream>>>(xb, w1b, b1, h, vt);
  attn<<<dim3(1024), dim3(256), 0, stream>>>(h, vt, pw, y);
  lnorm<false><<<dim3(1024), dim3(256), 0, stream>>>(y, g1, be1, l1);
  gemm_bt2<<<dim3(512), dim3(256), 0, stream>>>(l1, w2b, b2, x, z);
  lnorm<true><<<dim3(1024), dim3(256), 0, stream>>>(z, g2, be2, d_out);
}

// Round 14
// 223.270 us; speedup vs baseline: 1.1364x; 1.0446x over previous
//
#include <hip/hip_runtime.h>
#include <hip/hip_bf16.h>

#define BN   2
#define SEQ  2048
#define DIM  1024
#define NH   16
#define HD   64
#define D4   4096
#define MAXS 4096

using bf16 = __hip_bfloat16;
typedef __bf16 bf16x8 __attribute__((ext_vector_type(8)));
typedef float  f32x4  __attribute__((ext_vector_type(4)));
typedef unsigned short us8 __attribute__((ext_vector_type(8)));

__device__ __forceinline__ float bf2f(bf16 v){ return __bfloat162float(v); }
__device__ __forceinline__ bf16  f2bf(float v){ return __float2bfloat16(v); }
__device__ __forceinline__ float silu_f(float v){
  const float e = __expf(-v);
  return v * __builtin_amdgcn_rcpf(1.f + e);
}

__device__ __forceinline__ void async16(void* lds, const void* g){
  __builtin_amdgcn_global_load_lds((const __attribute__((address_space(1))) void*)g,
                                   (__attribute__((address_space(3))) void*)lds, 16, 0, 0);
}
__device__ __forceinline__ f32x4 mfma16(bf16x8 a, bf16x8 b, f32x4 c){
  return __builtin_amdgcn_mfma_f32_16x16x32_bf16(a, b, c, 0, 0, 0);
}

// ---------------- fp32 -> bf16 convert (3 arrays, 1 launch; 8 floats/thread) --------
__global__ __launch_bounds__(256) void f2bk3(
    const float* __restrict__ a, bf16* __restrict__ ao, int na,
    const float* __restrict__ b, bf16* __restrict__ bo, int nb,
    const float* __restrict__ c, bf16* __restrict__ co)
{
  int i = (blockIdx.x * 256 + threadIdx.x) * 8;
  const float* in; bf16* out;
  if (i < na){ in = a; out = ao; }
  else if (i < na + nb){ in = b; out = bo; i -= na; }
  else { in = c; out = co; i -= na + nb; }
  const float4 v0 = *(const float4*)(in + i);
  const float4 v1 = *(const float4*)(in + i + 4);
  us8 o;
  bf16 t;
  t = f2bf(v0.x); o[0] = *(unsigned short*)&t;
  t = f2bf(v0.y); o[1] = *(unsigned short*)&t;
  t = f2bf(v0.z); o[2] = *(unsigned short*)&t;
  t = f2bf(v0.w); o[3] = *(unsigned short*)&t;
  t = f2bf(v1.x); o[4] = *(unsigned short*)&t;
  t = f2bf(v1.y); o[5] = *(unsigned short*)&t;
  t = f2bf(v1.z); o[6] = *(unsigned short*)&t;
  t = f2bf(v1.w); o[7] = *(unsigned short*)&t;
  *(us8*)((unsigned short*)out + i) = o;
}

// ---------------- GEMM1: C = silu(A @ W^T + bias); v-tiles write transposed vt --------
// R19: 512-thread block, SAME 128^2 tile / BK=64 / 2-barrier structure. 8 waves in
// 4x2 (wr=wave&3 -> 32 rows, wc=wave>>2 -> 64 cols). Per-wave regs: acc 64->32 AGPR,
// operands 32->24 VGPR (gfx950 unified file: old 124 VGPR + 64 AGPR = ~188 -> only
// 2 waves/SIMD, the hidden occupancy cap). Target ~100 total -> 4 waves/SIMD ->
// 16 waves/CU (2 blocks x 8 waves), 2x residency. Staging: 1 async16 per wave per
// Al/Bl sub-tile (16 rows; srow/sg swizzle key depends only on row%16 - unchanged).
template<int NTOT>
__global__ __launch_bounds__(512) void gemm_bt(
    const bf16* __restrict__ A, const bf16* __restrict__ W,
    const float* __restrict__ bias, bf16* __restrict__ outb, bf16* __restrict__ vt)
{
  constexpr int K = DIM;
  const int ntiles = NTOT / 128;
  const int m0 = (int)(blockIdx.x / ntiles) * 128;
  const int n0 = (int)(blockIdx.x % ntiles) * 128;
  __shared__ bf16 Al[2*128*32];
  __shared__ bf16 Bl[2*128*32];
  const int tid = threadIdx.x, wave = tid>>6, lane = tid&63;
  const int quad = lane>>4, l16 = lane&15;
  const int srow = lane>>2;
  const int sg   = ((lane&3) ^ ((lane>>3)&3)) * 8;
  const int wr = wave & 3, wc = wave >> 2;       // 4x2 wave grid
  const int rkey = ((l16>>1)&3);

  f32x4 acc[2][4];
  #pragma unroll
  for (int i=0;i<2;i++)
    #pragma unroll
    for (int j=0;j<4;j++) acc[i][j] = (f32x4){0.f,0.f,0.f,0.f};

  const bf16* aB = A + m0*K;
  const bf16* wB = W + n0*K;

  for (int k0 = 0; k0 < K; k0 += 64){
    #pragma unroll
    for (int s=0;s<2;s++){
      const int kc = k0 + s*32;
      async16(&Al[s*4096 + wave*512], aB + (wave*16 + srow)*K + kc + sg);
      async16(&Bl[s*4096 + wave*512], wB + (wave*16 + srow)*K + kc + sg);
    }
    __syncthreads();
    #pragma unroll
    for (int s=0;s<2;s++){
      bf16x8 af[2], bv[4];
      #pragma unroll
      for (int mt=0;mt<2;mt++) af[mt] = *(const bf16x8*)&Al[s*4096 + (wr*32+mt*16+l16)*32 + (quad ^ rkey)*8];
      #pragma unroll
      for (int nt=0;nt<4;nt++) bv[nt] = *(const bf16x8*)&Bl[s*4096 + (wc*64+nt*16+l16)*32 + (quad ^ rkey)*8];
      #pragma unroll
      for (int mt=0;mt<2;mt++)
        #pragma unroll
        for (int nt=0;nt<4;nt++)
          acc[mt][nt] = mfma16(af[mt], bv[nt], acc[mt][nt]);
    }
    __syncthreads();
  }

  const bool vtile = (NTOT == 4096) && (n0 >= 3*DIM);
  if (!vtile){
    #pragma unroll
    for (int mt=0;mt<2;mt++){
      #pragma unroll
      for (int nt=0;nt<4;nt++){
        const int row = m0 + wr*32 + mt*16 + quad*4;
        const int col = n0 + wc*64 + nt*16 + l16;
        const float bvv = bias[col];
        #pragma unroll
        for (int r=0;r<4;r++){
          float v = silu_f(acc[mt][nt][r] + bvv);
          outb[(row+r)*NTOT + col] = f2bf(v);
        }
      }
    }
  } else {
    // v slice: write transposed directly to vt[b][hh][d][s] (4 consecutive s -> 8B store)
    #pragma unroll
    for (int mt=0;mt<2;mt++){
      #pragma unroll
      for (int nt=0;nt<4;nt++){
        const int row = m0 + wr*32 + mt*16 + quad*4;
        const int colg = n0 + wc*64 + nt*16 + l16;
        const float bvv = bias[colg];
        const int col = colg - 3*DIM;
        const int hh = col >> 6, d = col & 63;
        const int bb = row >> 11, sl = row & 2047;
        ushort4 o;
        float v0 = silu_f(acc[mt][nt][0] + bvv);
        float v1 = silu_f(acc[mt][nt][1] + bvv);
        float v2 = silu_f(acc[mt][nt][2] + bvv);
        float v3 = silu_f(acc[mt][nt][3] + bvv);
        bf16 t0=f2bf(v0), t1=f2bf(v1), t2=f2bf(v2), t3=f2bf(v3);
        o.x=*(unsigned short*)&t0; o.y=*(unsigned short*)&t1;
        o.z=*(unsigned short*)&t2; o.w=*(unsigned short*)&t3;
        *(ushort4*)&vt[((bb*NH + hh)*HD + d)*SEQ + sl] = o;
      }
    }
  }
}

// ---------------- GEMM2: z = A @ W^T + bias + resid, 128x64 tile, fp32 out ----------
// BK=128 as FOUR contiguous BK=32 sub-tiles (R11: verified pass). Grid 512 = 2
// blocks/CU grid-capped, so the 48KB LDS costs no occupancy. 16 barrier-pairs.
__global__ __launch_bounds__(256) void gemm_bt2(
    const bf16* __restrict__ A, const bf16* __restrict__ W,
    const float* __restrict__ bias, const float* __restrict__ resid,
    float* __restrict__ outf)
{
  constexpr int K = DIM, NTOT = DIM;
  const int ntiles = NTOT / 64;
  const int m0 = (int)(blockIdx.x / ntiles) * 128;
  const int n0 = (int)(blockIdx.x % ntiles) * 64;
  __shared__ bf16 Al[4*128*32];
  __shared__ bf16 Bl[4*64*32];
  const int tid = threadIdx.x, wave = tid>>6, lane = tid&63;
  const int quad = lane>>4, l16 = lane&15;
  const int srow = lane>>2;
  const int sg   = ((lane&3) ^ ((lane>>3)&3)) * 8;
  const int wm = wave*32;
  const int rkey = ((l16>>1)&3);

  f32x4 acc[2][4];
  #pragma unroll
  for (int i=0;i<2;i++)
    #pragma unroll
    for (int j=0;j<4;j++) acc[i][j] = (f32x4){0.f,0.f,0.f,0.f};

  const bf16* aB = A + m0*K;
  const bf16* wB = W + n0*K;

  for (int k0 = 0; k0 < K; k0 += 128){
    #pragma unroll
    for (int s=0;s<4;s++){
      const int kc = k0 + s*32;
      async16(&Al[s*4096 + wave*1024      ], aB + (wave*32      + srow)*K + kc + sg);
      async16(&Al[s*4096 + wave*1024 + 512], aB + (wave*32 + 16 + srow)*K + kc + sg);
      async16(&Bl[s*2048 + wave*512       ], wB + (wave*16      + srow)*K + kc + sg);
    }
    __syncthreads();
    #pragma unroll
    for (int s=0;s<4;s++){
      bf16x8 af[2], bv[4];
      #pragma unroll
      for (int mt=0;mt<2;mt++) af[mt] = *(const bf16x8*)&Al[s*4096 + (wm+mt*16+l16)*32 + (quad ^ rkey)*8];
      #pragma unroll
      for (int nt=0;nt<4;nt++) bv[nt] = *(const bf16x8*)&Bl[s*2048 + (nt*16+l16)*32 + (quad ^ rkey)*8];
      #pragma unroll
      for (int mt=0;mt<2;mt++)
        #pragma unroll
        for (int nt=0;nt<4;nt++)
          acc[mt][nt] = mfma16(af[mt], bv[nt], acc[mt][nt]);
    }
    __syncthreads();
  }

  #pragma unroll
  for (int mt=0;mt<2;mt++){
    #pragma unroll
    for (int nt=0;nt<4;nt++){
      const int row = m0 + wm + mt*16 + quad*4;
      const int col = n0 + nt*16 + l16;
      const float bvv = bias[col];
      #pragma unroll
      for (int r=0;r<4;r++){
        outf[(row+r)*NTOT + col] = acc[mt][nt][r] + bvv + resid[(row+r)*NTOT + col];
      }
    }
  }
}

// ---------------- attention (R7 verbatim: best verified attn) ----------------
// grid 1024 = 32 (b,h) groups x 32 q-tiles. g = bid&31 (XCD affinity), qt =
// 31-(bid>>5) (global LPT + backfill tail). Separate Pl (50KB LDS, 3 blocks/CU).
// Lessons: V LDS-staged (R6); full-batch P (R8); no waves-per-EU hint (R2).
__global__ __launch_bounds__(256) void attn(
    const bf16* __restrict__ h, const bf16* __restrict__ vt,
    const float* __restrict__ pw, bf16* __restrict__ y)
{
  const int bid = blockIdx.x;
  const int g  = bid & 31;                 // (b,head) group 0..31
  const int qt = 31 - (bid >> 5);          // global longest-first
  const int hh = g & 15, b = g >> 4;

  __shared__ __align__(16) char smem[16384 + 16384 + 17408 + 1024];
  bf16*  Kl  = (bf16*)smem;
  bf16*  Vl  = (bf16*)(smem + 16384);
  bf16*  Pl  = (bf16*)(smem + 32768);
  float* pwl = (float*)(smem + 50176);

  const int tid = threadIdx.x, wave = tid>>6, lane = tid&63;
  const int quad = lane>>4, l16 = lane&15;

  const bf16* kgb = h + b*SEQ*D4 + 2*DIM + hh*HD;
  const bf16* vgb = vt + (b*NH + hh)*HD*SEQ;
  const int krow8 = lane>>3;
  const int kgo   = ((lane&7) ^ krow8) * 8;
  const int vrow4 = lane>>4;

  const int q0 = qt * 64;

  const bf16* qbase = h + (b*SEQ + q0 + wave*16 + l16)*D4 + DIM + hh*HD;
  bf16x8 qf[2];
  qf[0] = *(const bf16x8*)(qbase + quad*8);
  qf[1] = *(const bf16x8*)(qbase + 32 + quad*8);

  f32x4 oacc[4];
  #pragma unroll
  for (int nt=0;nt<4;nt++) oacc[nt] = (f32x4){0.f,0.f,0.f,0.f};

  const int kmax = q0 + 64;

  // ---- prologue prefetch (k0 = 0) into regs ----
  bf16x8 kreg[4], vreg[4];
  float pv;
  #pragma unroll
  for (int t=0;t<4;t++)
    kreg[t] = *(const bf16x8*)(kgb + (wave*32 + t*8 + krow8)*D4 + kgo);
  #pragma unroll
  for (int t=0;t<4;t++){
    const int vg = ((lane&15) ^ (t*4 + vrow4)) * 8;
    vreg[t] = *(const bf16x8*)(vgb + (wave*16 + t*4 + vrow4)*SEQ + vg);
  }
  pv = pw[MAXS - 1 - q0 - 63 + tid];

  for (int k0 = 0; k0 < kmax; k0 += 128){
    __syncthreads();   // b1: all waves done reading Kl/Vl/pwl from previous iter
    #pragma unroll
    for (int t=0;t<4;t++)
      *(bf16x8*)&Kl[(wave*32 + t*8)*64 + lane*8] = kreg[t];
    #pragma unroll
    for (int t=0;t<4;t++)
      *(bf16x8*)&Vl[(wave*16 + t*4)*128 + lane*8] = vreg[t];
    pwl[tid] = pv;
    __syncthreads();   // b2: staged tile visible

    if (k0 + 128 < kmax){
      const int kn = k0 + 128;
      #pragma unroll
      for (int t=0;t<4;t++)
        kreg[t] = *(const bf16x8*)(kgb + (kn + wave*32 + t*8 + krow8)*D4 + kgo);
      #pragma unroll
      for (int t=0;t<4;t++){
        const int vg = ((lane&15) ^ (t*4 + vrow4)) * 8;
        vreg[t] = *(const bf16x8*)(vgb + (wave*16 + t*4 + vrow4)*SEQ + kn + vg);
      }
      pv = pw[MAXS - 1 + kn - q0 - 63 + tid];
    }

    // S^T = K @ Q^T  (m=128 kpos as 8 nt-frags, n=16 qrows, k=64)
    f32x4 sacc[8];
    #pragma unroll
    for (int nt=0;nt<8;nt++) sacc[nt] = (f32x4){0.f,0.f,0.f,0.f};
    __builtin_amdgcn_s_setprio(1);
    #pragma unroll
    for (int ks=0;ks<2;ks++){
      #pragma unroll
      for (int nt=0;nt<8;nt++){
        bf16x8 kf = *(const bf16x8*)&Kl[(nt*16 + l16)*64 + ((ks*4 + quad) ^ (l16&7))*8];
        sacc[nt] = mfma16(kf, qf[ks], sacc[nt]);   // A=K, B=Q^T  -> C = S^T
      }
    }
    __builtin_amdgcn_s_setprio(0);

    // bias + silu + causal; lane holds 4 consecutive kpos for fixed qrow=l16
    bf16* Plw = Pl + wave*(16*136);
    const int dq = q0 - k0;
    const int qrl = wave*16 + l16;
    if (dq >= 127){
      #pragma unroll
      for (int nt=0;nt<8;nt++){
        const int kb = nt*16 + quad*4;
        ushort4 o; bf16 tb[4];
        #pragma unroll
        for (int r=0;r<4;r++){
          const int d = kb + r - qrl;
          const float bias = pwl[d + 63];
          tb[r] = f2bf(silu_f(sacc[nt][r] + bias));
        }
        o.x=*(unsigned short*)&tb[0]; o.y=*(unsigned short*)&tb[1];
        o.z=*(unsigned short*)&tb[2]; o.w=*(unsigned short*)&tb[3];
        *(ushort4*)&Plw[l16*136 + kb] = o;
      }
    } else {
      #pragma unroll
      for (int nt=0;nt<8;nt++){
        const int kb = nt*16 + quad*4;
        ushort4 o; bf16 tb[4];
        #pragma unroll
        for (int r=0;r<4;r++){
          const int d = kb + r - qrl;
          const float bias = pwl[d + 63];
          const float sv = silu_f(sacc[nt][r] + bias);
          tb[r] = f2bf((d <= dq) ? sv : 0.f);
        }
        o.x=*(unsigned short*)&tb[0]; o.y=*(unsigned short*)&tb[1];
        o.z=*(unsigned short*)&tb[2]; o.w=*(unsigned short*)&tb[3];
        *(ushort4*)&Plw[l16*136 + kb] = o;
      }
    }

    // O += P @ V  (m=16 qrows, n=64 d, k=128 kpos); same-wave LDS RAW, no barrier.
    __builtin_amdgcn_s_setprio(1);
    #pragma unroll
    for (int ks=0;ks<4;ks++){
      bf16x8 pf = *(const bf16x8*)&Plw[l16*136 + ks*32 + quad*8];
      #pragma unroll
      for (int nt=0;nt<4;nt++){
        bf16x8 vf = *(const bf16x8*)&Vl[(nt*16 + l16)*128 + ((ks*4 + quad) ^ l16)*8];
        oacc[nt] = mfma16(pf, vf, oacc[nt]);
      }
    }
    __builtin_amdgcn_s_setprio(0);
  }

  // epilogue: multiply by u, write y
  const int qrow = q0 + wave*16 + quad*4;
  #pragma unroll
  for (int nt=0;nt<4;nt++){
    const int c = hh*HD + nt*16 + l16;
    #pragma unroll
    for (int r=0;r<4;r++){
      const int srow = b*SEQ + qrow + r;
      const float uu = bf2f(h[srow*D4 + c]);
      y[srow*DIM + c] = f2bf(oacc[nt][r] * uu);
    }
  }
}

// NOTE on pwl indexing: d = (kb + r) - (wave*16 + l16), window W0 = MAXS-1+k0-q0-63
// gives pwl[d + 63] with d in [-63, 127] -> idx in [0,190]. W0+tid stays within
// pw's 2*MAXS-1 = 8191 entries (W0 in [2048,4032], +255 max = 4287).

// ---------------- row layernorm over D=1024 (wave-per-row, no LDS/barriers) ----
template<bool FP32>
__global__ __launch_bounds__(256) void lnorm(const void* __restrict__ in,
    const float* __restrict__ g, const float* __restrict__ be, void* __restrict__ out)
{
  const int wave = threadIdx.x>>6, lane = threadIdx.x&63;
  const int row = blockIdx.x*4 + wave;
  float v[16];
  if (FP32){
    const float* p = (const float*)in + row*DIM;
    #pragma unroll
    for (int j=0;j<4;j++){
      const float4 t = *(const float4*)(p + j*256 + lane*4);
      v[j*4+0]=t.x; v[j*4+1]=t.y; v[j*4+2]=t.z; v[j*4+3]=t.w;
    }
  } else {
    const unsigned short* p = (const unsigned short*)in + row*DIM;
    #pragma unroll
    for (int j=0;j<2;j++){
      const us8 t = *(const us8*)(p + j*512 + lane*8);
      #pragma unroll
      for (int k=0;k<8;k++){
        unsigned short u = t[k];
        v[j*8+k] = bf2f(*(bf16*)&u);
      }
    }
  }
  float s = 0.f, ss = 0.f;
  #pragma unroll
  for (int e=0;e<16;e++){ s += v[e]; ss += v[e]*v[e]; }
  #pragma unroll
  for (int off=1; off<64; off<<=1){
    s  += __shfl_xor(s, off);
    ss += __shfl_xor(ss, off);
  }
  const float mu   = s * (1.f/DIM);
  const float var  = ss * (1.f/DIM) - mu*mu;
  const float rstd = rsqrtf(var + 1e-5f);
  if (FP32){
    float* q = (float*)out + row*DIM;
    #pragma unroll
    for (int j=0;j<4;j++){
      const int c = j*256 + lane*4;
      const float4 gv = *(const float4*)(g + c);
      const float4 bv = *(const float4*)(be + c);
      float4 o;
      o.x = (v[j*4+0]-mu)*rstd*gv.x + bv.x;
      o.y = (v[j*4+1]-mu)*rstd*gv.y + bv.y;
      o.z = (v[j*4+2]-mu)*rstd*gv.z + bv.z;
      o.w = (v[j*4+3]-mu)*rstd*gv.w + bv.w;
      *(float4*)(q + c) = o;
    }
  } else {
    unsigned short* q = (unsigned short*)out + row*DIM;
    #pragma unroll
    for (int j=0;j<2;j++){
      const int c = j*512 + lane*8;
      us8 o;
      #pragma unroll
      for (int k=0;k<8;k++){
        const float ov = (v[j*8+k]-mu)*rstd*g[c+k] + be[c+k];
        bf16 t = f2bf(ov);
        o[k] = *(unsigned short*)&t;
      }
      *(us8*)(q + c) = o;
    }
  }
}

extern "C" void kernel_launch(void* const* d_in, const int* in_sizes, int n_in,
                              void* d_out, int out_size, void* d_ws, size_t ws_size,
                              hipStream_t stream)
{
  const float* x   = (const float*)d_in[0];
  const float* w1  = (const float*)d_in[2];
  const float* b1  = (const float*)d_in[3];
  const float* w2  = (const float*)d_in[4];
  const float* b2  = (const float*)d_in[5];
  const float* g1  = (const float*)d_in[6];
  const float* be1 = (const float*)d_in[7];
  const float* g2  = (const float*)d_in[8];
  const float* be2 = (const float*)d_in[9];
  const float* pw  = (const float*)d_in[10];

  char* ws = (char*)d_ws;
  bf16*  h   = (bf16*)(ws);
  bf16*  vt  = (bf16*)(ws + (32u<<20));
  bf16*  y   = (bf16*)(ws + (40u<<20));
  bf16*  xb  = (bf16*)(ws + (48u<<20));
  bf16*  w1b = (bf16*)(ws + (56u<<20));
  bf16*  w2b = (bf16*)(ws + (64u<<20));
  bf16*  l1  = (bf16*)(ws + (66u<<20));
  float* z   = (float*)(ws + (74u<<20));

  const int NX  = BN*SEQ*DIM;
  const int NW1 = 4*DIM*DIM;
  const int NW2 = DIM*DIM;
  f2bk3<<<dim3((NX+NW1+NW2)/2048), dim3(256), 0, stream>>>(x, xb, NX, w1, w1b, NW1, w2, w2b);

  gemm_bt<4096><<<dim3(1024), dim3(512), 0, stream>>>(xb, w1b, b1, h, vt);
  attn<<<dim3(1024), dim3(256), 0, stream>>>(h, vt, pw, y);
  lnorm<false><<<dim3(1024), dim3(256), 0, stream>>>(y, g1, be1, l1);
  gemm_bt2<<<dim3(512), dim3(256), 0, stream>>>(l1, w2b, b2, x, z);
  lnorm<true><<<dim3(1024), dim3(256), 0, stream>>>(z, g2, be2, d_out);
}